// Round 11
// baseline (718.538 us; speedup 1.0000x reference)
//
#include <hip/hip_runtime.h>
#include <cstddef>

#define HQ 2048
#define NKVH 4
#define HDIM 128
#define QKV_N 3072
#define ATT_SCALE 0.08838834764831845f
#define KSPLIT 16
#define CHUNK 64
#define NCH 64
#define ATT_GRID 512
#define ATT_NW (ATT_GRID * 4)  // total waves

__device__ __forceinline__ float4 f4max(float4 a, float4 b) {
  return make_float4(fmaxf(a.x, b.x), fmaxf(a.y, b.y), fmaxf(a.z, b.z), fmaxf(a.w, b.w));
}

// ---------------------------------------------------------------------------
// Projection / reduce: unchanged (R6).
// ---------------------------------------------------------------------------
template <int N>
__global__ __launch_bounds__(256) void proj_kernel(const float* __restrict__ X,
                                                   const float* __restrict__ W,
                                                   float* __restrict__ part) {
  __shared__ union {
    float x[32][128];
    float red[32][4][64];
  } sm;
  const int t = threadIdx.x;
  const int c0 = blockIdx.x << 6;
  const int ksb = blockIdx.y;
  const int k0 = ksb << 7;
  const int c = t & 63;
  const int ksub = t >> 6;

#pragma unroll
  for (int i = 0; i < 4; ++i) {
    const int id = t + (i << 8);
    const int bb = id >> 5, kk = (id & 31) << 2;
    *reinterpret_cast<float4*>(&sm.x[bb][kk]) =
        *reinterpret_cast<const float4*>(X + bb * HQ + k0 + kk);
  }
  __syncthreads();

  float acc[32];
#pragma unroll
  for (int b = 0; b < 32; ++b) acc[b] = 0.f;

#pragma unroll
  for (int kk4 = 0; kk4 < 8; ++kk4) {
    const int kk = (ksub << 5) + (kk4 << 2);
    const float* wp = W + (size_t)(k0 + kk) * N + c0 + c;
    const float w0 = wp[0];
    const float w1 = wp[N];
    const float w2 = wp[2 * N];
    const float w3 = wp[3 * N];
#pragma unroll
    for (int b = 0; b < 32; ++b) {
      const float4 x4 = *reinterpret_cast<const float4*>(&sm.x[b][kk]);
      acc[b] = fmaf(x4.x, w0, acc[b]);
      acc[b] = fmaf(x4.y, w1, acc[b]);
      acc[b] = fmaf(x4.z, w2, acc[b]);
      acc[b] = fmaf(x4.w, w3, acc[b]);
    }
  }
  __syncthreads();
#pragma unroll
  for (int b = 0; b < 32; ++b) sm.red[b][ksub][c] = acc[b];
  __syncthreads();
#pragma unroll
  for (int i = 0; i < 8; ++i) {
    const int o = t + (i << 8);
    const int b = o >> 6, cc = o & 63;
    const float v = sm.red[b][0][cc] + sm.red[b][1][cc] + sm.red[b][2][cc] + sm.red[b][3][cc];
    part[(size_t)(ksb * 32 + b) * N + c0 + cc] = v;
  }
}

template <int NCOL, bool HAS_BIAS>
__global__ __launch_bounds__(256) void reduce_kernel(const float* __restrict__ part,
                                                     const float* __restrict__ bias,
                                                     float* __restrict__ out) {
  const int o = blockIdx.x * 256 + threadIdx.x;
  constexpr int total = 32 * NCOL;
  float s = 0.f;
#pragma unroll
  for (int ks = 0; ks < KSPLIT; ++ks) s += part[(size_t)ks * total + o];
  if (HAS_BIAS) s += bias[o % NCOL];
  out[o] = s;
}

// ---------------------------------------------------------------------------
// Worklist: compact active (b,kvh,chunk) items. 1 block.
// ---------------------------------------------------------------------------
__global__ __launch_bounds__(256) void worklist_kernel(const int* __restrict__ seq_lens,
                                                       int* __restrict__ wl,
                                                       int* __restrict__ wlcount) {
  __shared__ int offs[32];
  const int t = threadIdx.x;
  if (t == 0) {
    int acc = 0;
    for (int b = 0; b < 32; ++b) {
      offs[b] = acc;
      acc += 4 * ((seq_lens[b] + 63) >> 6);
    }
    *wlcount = acc;
  }
  __syncthreads();
  for (int b = 0; b < 32; ++b) {
    const int nch = (seq_lens[b] + 63) >> 6;
    const int tot = nch << 2;
    const int base = offs[b];
    for (int idx = t; idx < tot; idx += 256) {
      const int kvh = idx / nch;
      const int chunk = idx - kvh * nch;
      wl[base + idx] = (b << 9) | (kvh << 7) | chunk;
    }
  }
}

// ---------------------------------------------------------------------------
// Attention helpers (per-wave, barrier-free).
// ---------------------------------------------------------------------------
__device__ __forceinline__ void load_q8(const float* __restrict__ qrow, int kvh, int l16,
                                        float4* qr) {
#pragma unroll
  for (int g = 0; g < 4; ++g) {
    const float* qp = qrow + ((kvh << 2) + g) * HDIM + (l16 << 2);
    qr[2 * g] = *reinterpret_cast<const float4*>(qp);
    qr[2 * g + 1] = *reinterpret_cast<const float4*>(qp + 64);
  }
}

__device__ __forceinline__ void load_k32(const float* __restrict__ cache,
                                         const float* __restrict__ knew, int b, int kvh, int slot,
                                         int base, int send, int rq, int l16, float4* ka) {
#pragma unroll
  for (int j = 0; j < 8; ++j) {
    int sg = base + (j << 2) + rq;
    sg = (sg < send) ? sg : (send - 1);
    const float* kp = ((sg == slot) ? knew
                                    : cache + (((size_t)((b << 12) + sg)) << 10) + (kvh << 7)) +
                      (l16 << 2);
    ka[2 * j] = *reinterpret_cast<const float4*>(kp);
    ka[2 * j + 1] = *reinterpret_cast<const float4*>(kp + 64);
  }
}

__device__ __forceinline__ void load_v32(const float* __restrict__ cache,
                                         const float* __restrict__ vnew, int b, int kvh, int slot,
                                         int base, int send, int l, float2* va) {
#pragma unroll
  for (int s = 0; s < 32; ++s) {
    int sg = base + s;
    sg = (sg < send) ? sg : (send - 1);
    const float* vp = (sg == slot)
                          ? vnew
                          : cache + (((size_t)((b << 12) + sg)) << 10) + 512 + (kvh << 7);
    va[s] = *reinterpret_cast<const float2*>(vp + (l << 1));
  }
}

__device__ __forceinline__ float dot8(float4 k0, float4 k1, float4 q0, float4 q1) {
  float s = fmaf(k0.x, q0.x, fmaf(k0.y, q0.y, fmaf(k0.z, q0.z, k0.w * q0.w)));
  return fmaf(k1.x, q1.x, fmaf(k1.y, q1.y, fmaf(k1.z, q1.z, fmaf(k1.w, q1.w, s))));
}

// scores for 32 rows (local rbase..rbase+31) -> raw scaled scores in ptw[0..31][4]
__device__ __forceinline__ void score32(const float4* ka, const float4* qr, int n, int rbase,
                                        int rq, int l16, float* __restrict__ ptw, float4& m4) {
#pragma unroll
  for (int j = 0; j < 8; ++j) {
    const float4 k0 = ka[2 * j], k1 = ka[2 * j + 1];
    float s0 = dot8(k0, k1, qr[0], qr[1]);
    float s1 = dot8(k0, k1, qr[2], qr[3]);
    float s2 = dot8(k0, k1, qr[4], qr[5]);
    float s3 = dot8(k0, k1, qr[6], qr[7]);
#pragma unroll
    for (int off = 1; off <= 8; off <<= 1) {
      s0 += __shfl_xor(s0, off);
      s1 += __shfl_xor(s1, off);
      s2 += __shfl_xor(s2, off);
      s3 += __shfl_xor(s3, off);
    }
    float4 sc = make_float4(s0 * ATT_SCALE, s1 * ATT_SCALE, s2 * ATT_SCALE, s3 * ATT_SCALE);
    const int rl = rbase + (j << 2) + rq;
    if (rl >= n) sc = make_float4(-1e30f, -1e30f, -1e30f, -1e30f);
    m4 = f4max(m4, sc);
    if (l16 == 0) *reinterpret_cast<float4*>(ptw + (((j << 2) + rq) << 2)) = sc;
  }
}

__device__ __forceinline__ float4 wavemax(float4 m) {
  m.x = fmaxf(m.x, __shfl_xor(m.x, 16));
  m.y = fmaxf(m.y, __shfl_xor(m.y, 16));
  m.z = fmaxf(m.z, __shfl_xor(m.z, 16));
  m.w = fmaxf(m.w, __shfl_xor(m.w, 16));
  m.x = fmaxf(m.x, __shfl_xor(m.x, 32));
  m.y = fmaxf(m.y, __shfl_xor(m.y, 32));
  m.z = fmaxf(m.z, __shfl_xor(m.z, 32));
  m.w = fmaxf(m.w, __shfl_xor(m.w, 32));
  return m;
}

__device__ __forceinline__ void pv32(const float* __restrict__ ptw, const float2* va, float4 M,
                                     float4& lsum, float4& accA, float4& accB) {
#pragma unroll
  for (int s = 0; s < 32; ++s) {
    const float4 raw = *reinterpret_cast<const float4*>(ptw + (s << 2));
    float4 e;
    e.x = __expf(raw.x - M.x);
    e.y = __expf(raw.y - M.y);
    e.z = __expf(raw.z - M.z);
    e.w = __expf(raw.w - M.w);
    lsum.x += e.x; lsum.y += e.y; lsum.z += e.z; lsum.w += e.w;
    const float2 vv = va[s];
    accA.x = fmaf(e.x, vv.x, accA.x); accA.y = fmaf(e.y, vv.x, accA.y);
    accA.z = fmaf(e.z, vv.x, accA.z); accA.w = fmaf(e.w, vv.x, accA.w);
    accB.x = fmaf(e.x, vv.y, accB.x); accB.y = fmaf(e.y, vv.y, accB.y);
    accB.z = fmaf(e.z, vv.y, accB.z); accB.w = fmaf(e.w, vv.y, accB.w);
  }
}

// ---------------------------------------------------------------------------
// Barrier-free flash-decode attention: ONE WAVE = ONE ITEM (64 rows),
// grid-stride over a compacted worklist, software-pipelined loads across
// halves and items. No __syncthreads anywhere -> no vmcnt(0) drains.
// ---------------------------------------------------------------------------
__global__ __launch_bounds__(256, 2) void attn_kernel(const float* __restrict__ cache,
                                                      const int* __restrict__ seq_lens,
                                                      const int* __restrict__ slot_map,
                                                      const float* __restrict__ qkv,
                                                      const int* __restrict__ wl,
                                                      const int* __restrict__ wlcount,
                                                      float* __restrict__ ml,
                                                      float* __restrict__ accp) {
  __shared__ float pt[4][32][4];

  const int t = threadIdx.x;
  const int w = t >> 6, l = t & 63;
  const int l16 = l & 15, rq = l >> 4;
  float* ptw = &pt[w][0][0];

  const int count = *wlcount;
  int i = (blockIdx.x << 2) + w;
  if (i >= count) return;

  // decode current item
  int it = wl[i];
  int b = it >> 9, kvh = (it >> 7) & 3, chunk = it & 127;
  int L = seq_lens[b];
  int start = chunk << 6;
  int n = min(CHUNK, L - start);
  int send = start + n;
  int slot = slot_map[b];
  const float* qrow = qkv + b * QKV_N;
  const float* knew = qrow + 2048 + (kvh << 7);
  const float* vnew = qrow + 2560 + (kvh << 7);

  float4 qr[8], ka[16];
  float2 va[32];
  load_q8(qrow, kvh, l16, qr);
  load_k32(cache, knew, b, kvh, slot, start, send, rq, l16, ka);
  load_v32(cache, vnew, b, kvh, slot, start, send, l, va);

  for (;;) {
    const bool hasNext = (i + ATT_NW) < count;
    const int itN = hasNext ? wl[i + ATT_NW] : 0;  // issued early, decoded later

    // ---- score H0 (rows 0..31) ----
    float4 m0 = make_float4(-1e30f, -1e30f, -1e30f, -1e30f);
    score32(ka, qr, n, 0, rq, l16, ptw, m0);

    // prefetch K H1 (rows 32..63)
    load_k32(cache, knew, b, kvh, slot, start + 32, send, rq, l16, ka);

    // decode next + issue its scalar-ish loads (hidden under PV/score below)
    int bN = 0, kvhN = 0, chunkN = 0, LN = 0, slotN = 0;
    const float *qrowN = nullptr, *knewN = nullptr, *vnewN = nullptr;
    if (hasNext) {
      bN = itN >> 9;
      kvhN = (itN >> 7) & 3;
      chunkN = itN & 127;
      LN = seq_lens[bN];
      slotN = slot_map[bN];
      qrowN = qkv + bN * QKV_N;
      knewN = qrowN + 2048 + (kvhN << 7);
      vnewN = qrowN + 2560 + (kvhN << 7);
    }

    m0 = wavemax(m0);
    asm volatile("s_waitcnt lgkmcnt(0)" ::: "memory");  // pt visible (wave-private)

    // ---- PV H0 ----
    float4 lsum = make_float4(0.f, 0.f, 0.f, 0.f);
    float4 accA = make_float4(0.f, 0.f, 0.f, 0.f);
    float4 accB = make_float4(0.f, 0.f, 0.f, 0.f);
    pv32(ptw, va, m0, lsum, accA, accB);

    // prefetch V H1
    load_v32(cache, vnew, b, kvh, slot, start + 32, send, l, va);

    // ---- score H1 (rows 32..63) ----
    float4 m1 = make_float4(-1e30f, -1e30f, -1e30f, -1e30f);
    score32(ka, qr, n, 32, rq, l16, ptw, m1);

    // prefetch next item's q + K H0 (ka/qr free after score H1)
    int startN = 0, nN = 0, sendN = 0;
    if (hasNext) {
      startN = chunkN << 6;
      nN = min(CHUNK, LN - startN);
      sendN = startN + nN;
      load_q8(qrowN, kvhN, l16, qr);
      load_k32(cache, knewN, bN, kvhN, slotN, startN, sendN, rq, l16, ka);
    }

    // online merge of half maxima
    m1 = wavemax(m1);
    const float4 M = f4max(m0, m1);
    float4 r0;
    r0.x = __expf(m0.x - M.x);
    r0.y = __expf(m0.y - M.y);
    r0.z = __expf(m0.z - M.z);
    r0.w = __expf(m0.w - M.w);
    accA.x *= r0.x; accA.y *= r0.y; accA.z *= r0.z; accA.w *= r0.w;
    accB.x *= r0.x; accB.y *= r0.y; accB.z *= r0.z; accB.w *= r0.w;
    lsum.x *= r0.x; lsum.y *= r0.y; lsum.z *= r0.z; lsum.w *= r0.w;

    asm volatile("s_waitcnt lgkmcnt(0)" ::: "memory");

    // ---- PV H1 ----
    pv32(ptw, va, M, lsum, accA, accB);

    // prefetch next item's V H0
    if (hasNext) load_v32(cache, vnewN, bN, kvhN, slotN, startN, sendN, l, va);

    // ---- write outputs for current item ----
    const int oslot = (((b << 2) | kvh) << 6) + chunk;
    float* ap = accp + (size_t)oslot * 512;
    *reinterpret_cast<float2*>(ap + (l << 1)) = make_float2(accA.x, accB.x);
    *reinterpret_cast<float2*>(ap + 128 + (l << 1)) = make_float2(accA.y, accB.y);
    *reinterpret_cast<float2*>(ap + 256 + (l << 1)) = make_float2(accA.z, accB.z);
    *reinterpret_cast<float2*>(ap + 384 + (l << 1)) = make_float2(accA.w, accB.w);
    if (l == 0) {
      *reinterpret_cast<float4*>(ml + (size_t)oslot * 8) = M;
      *reinterpret_cast<float4*>(ml + (size_t)oslot * 8 + 4) = lsum;
    }

    if (!hasNext) break;
    i += ATT_NW;
    it = itN; b = bN; kvh = kvhN; chunk = chunkN; L = LN; slot = slotN;
    start = startN; n = nN; send = sendN;
    qrow = qrowN; knew = knewN; vnew = vnewN;
  }
}

// ---------------------------------------------------------------------------
// Combine chunk partials. grid 512 = (b,kvh,g), block 128 (d). [unchanged]
// ---------------------------------------------------------------------------
__global__ __launch_bounds__(128) void combine_kernel(const int* __restrict__ seq_lens,
                                                      const float* __restrict__ ml,
                                                      const float* __restrict__ accp,
                                                      float* __restrict__ attn) {
  const int blk = blockIdx.x;
  const int g = blk & 3, kvh = (blk >> 2) & 3, b = blk >> 4;
  const int d = threadIdx.x;
  const int L = seq_lens[b];
  const int nch = (L + CHUNK - 1) >> 6;
  const int base = (b * 4 + kvh) * NCH;

  float M = -1e30f;
  for (int c = 0; c < nch; ++c) M = fmaxf(M, ml[(size_t)(base + c) * 8 + g]);
  float osum = 0.f, lsum = 0.f;
  for (int c = 0; c < nch; ++c) {
    const int idx = base + c;
    const float mc = ml[(size_t)idx * 8 + g];
    const float lc = ml[(size_t)idx * 8 + 4 + g];
    const float wgt = __expf(mc - M);
    lsum = fmaf(lc, wgt, lsum);
    osum = fmaf(wgt, accp[(size_t)idx * 512 + g * 128 + d], osum);
  }
  attn[(size_t)b * HQ + kvh * 512 + g * 128 + d] = osum / lsum;
}

// ---------------------------------------------------------------------------
extern "C" void kernel_launch(void* const* d_in, const int* in_sizes, int n_in,
                              void* d_out, int out_size, void* d_ws, size_t ws_size,
                              hipStream_t stream) {
  const float* hidden = (const float*)d_in[0];
  const float* cache = (const float*)d_in[2];
  const int* slot_map = (const int*)d_in[3];
  const int* seq_lens = (const int*)d_in[4];
  const float* Wqkv = (const float*)d_in[5];
  const float* bqkv = (const float*)d_in[6];
  const float* Wo = (const float*)d_in[7];
  float* out = (float*)d_out;
  float* ws = (float*)d_ws;

  float* qkv_part = ws;            // 16*32*3072 = 1,572,864
  float* qkv      = ws + 1572864;  // 98,304
  float* ml       = ws + 1671168;  // 8192*8 = 65,536
  float* accp     = ws + 1736704;  // 8192*512 = 4,194,304
  float* attn     = ws + 5931008;  // 65,536
  float* o_part   = ws + 5996544;  // 16*32*2048 = 1,048,576
  int*   wl       = (int*)(ws + 7045120);  // 8192 ints
  int*   wlcount  = (int*)(ws + 7053312);  // 1 int

  worklist_kernel<<<1, 256, 0, stream>>>(seq_lens, wl, wlcount);
  proj_kernel<QKV_N><<<dim3(48, KSPLIT), 256, 0, stream>>>(hidden, Wqkv, qkv_part);
  reduce_kernel<QKV_N, true><<<384, 256, 0, stream>>>(qkv_part, bqkv, qkv);
  attn_kernel<<<ATT_GRID, 256, 0, stream>>>(cache, seq_lens, slot_map, qkv, wl, wlcount, ml, accp);
  combine_kernel<<<512, 128, 0, stream>>>(seq_lens, ml, accp, attn);
  proj_kernel<HQ><<<dim3(32, KSPLIT), 256, 0, stream>>>(attn, Wo, o_part);
  reduce_kernel<HQ, false><<<256, 256, 0, stream>>>(o_part, nullptr, out);
}